// Round 3
// baseline (331.122 us; speedup 1.0000x reference)
//
#include <hip/hip_runtime.h>

#define N 4096
#define C 64
#define B 4

typedef __attribute__((ext_vector_type(8))) short short8;
typedef __attribute__((ext_vector_type(4))) float f32x4;
typedef unsigned long long u64;

#define MFMA16(a, b, c) __builtin_amdgcn_mfma_f32_16x16x32_bf16(a, b, c, 0, 0, 0)

__device__ __forceinline__ short f2bf(float f) {
    unsigned u = __builtin_bit_cast(unsigned, f);
    u += 0x7fffu + ((u >> 16) & 1u);   // RNE; inputs finite
    return (short)(u >> 16);
}

// -------- adjacency bitmask: adj = (0<d<0.5) | eye, one uint64 per (i, j/64) --------
__global__ __launch_bounds__(256) void mask_kernel(const float* __restrict__ dist,
                                                   u64* __restrict__ msk) {
    const int wave = threadIdx.x >> 6, lane = threadIdx.x & 63;
    const int i = blockIdx.x * 4 + wave;
    const float* row = dist + (size_t)i * N;
#pragma unroll 4
    for (int jb = 0; jb < N / 64; jb++) {
        float d = row[jb * 64 + lane];               // coalesced 256B per wave
        u64 m = __ballot(d > 0.f && d < 0.5f);
        int dj = i - jb * 64;
        if (dj >= 0 && dj < 64) m |= (1ull << dj);   // diagonal
        if (lane == 0) msk[(size_t)i * (N / 64) + jb] = m;
    }
}

// -------- Phase A: projection (coalesced writes only; no transpose here) --------
__global__ __launch_bounds__(256) void proj_kernel(
    const float* __restrict__ x,       // B,N,C
    const float* __restrict__ proj_w,  // N,C,C
    const float* __restrict__ proj_b,  // N,C
    const float* __restrict__ a_w,     // N,2C
    short* __restrict__ h_bf,          // B,N,C
    short* __restrict__ a_srcb,        // N,C
    float* __restrict__ e2)            // B,N
{
    __shared__ float lds_x[B][C];
    __shared__ float lds_acc[4][B][C];

    const int tid = threadIdx.x;
    const int wave = tid >> 6;
    const int lane = tid & 63;
    const int n = blockIdx.x;

    lds_x[wave][lane] = x[((size_t)wave * N + n) * C + lane];  // wave==b
    __syncthreads();

    const int o4 = (lane & 15) * 4;
    const int cl = lane >> 4;
    const float* Wn = proj_w + (size_t)n * C * C;

    float4 acc[B];
#pragma unroll
    for (int b = 0; b < B; b++) acc[b] = make_float4(0.f, 0.f, 0.f, 0.f);

#pragma unroll
    for (int i = 0; i < 4; i++) {
        int c = wave * 16 + i * 4 + cl;
        float4 wv = *(const float4*)(Wn + c * C + o4);  // wave reads 1KB contiguous
#pragma unroll
        for (int b = 0; b < B; b++) {
            float xc = lds_x[b][c];
            acc[b].x = fmaf(xc, wv.x, acc[b].x);
            acc[b].y = fmaf(xc, wv.y, acc[b].y);
            acc[b].z = fmaf(xc, wv.z, acc[b].z);
            acc[b].w = fmaf(xc, wv.w, acc[b].w);
        }
    }
#pragma unroll
    for (int b = 0; b < B; b++) {
#pragma unroll
        for (int off = 16; off < 64; off <<= 1) {
            acc[b].x += __shfl_xor(acc[b].x, off, 64);
            acc[b].y += __shfl_xor(acc[b].y, off, 64);
            acc[b].z += __shfl_xor(acc[b].z, off, 64);
            acc[b].w += __shfl_xor(acc[b].w, off, 64);
        }
        if (lane < 16) *(float4*)(&lds_acc[wave][b][o4]) = acc[b];
    }
    __syncthreads();

    {
        const int b = wave, o = lane;
        float hval = proj_b[(size_t)n * C + o] + lds_acc[0][b][o] + lds_acc[1][b][o] +
                     lds_acc[2][b][o] + lds_acc[3][b][o];
        float adst = a_w[(size_t)n * (2 * C) + C + o];
        h_bf[((size_t)b * N + n) * C + o] = f2bf(hval);
        float prod = hval * adst;
#pragma unroll
        for (int off = 32; off; off >>= 1) prod += __shfl_xor(prod, off, 64);
        if (lane == 0) e2[b * N + n] = prod;
        if (tid < C) a_srcb[(size_t)n * C + tid] = f2bf(a_w[(size_t)n * (2 * C) + tid]);
    }
}

// -------- h (B,N,C) -> hT (B,C,N), both sides coalesced via LDS tile --------
__global__ __launch_bounds__(256) void transpose_kernel(const short* __restrict__ h_bf,
                                                        short* __restrict__ hT_bf) {
    __shared__ short tile[64][72];
    const int t = threadIdx.x;
    const int b = blockIdx.y;
    const int n0 = blockIdx.x * 64;
    {
        int r = t >> 2, cs = (t & 3) * 16;
        const short* src = h_bf + ((size_t)b * N + n0 + r) * C + cs;
#pragma unroll
        for (int q = 0; q < 4; q++)
            *(short4*)&tile[r][cs + q * 4] = *(const short4*)(src + q * 4);
    }
    __syncthreads();
    {
        int c = t >> 2, ns = (t & 3) * 16;
        short v[16];
#pragma unroll
        for (int k = 0; k < 16; k++) v[k] = tile[ns + k][c];
        short* dst = hT_bf + (size_t)b * C * N + (size_t)c * N + n0 + ns;
        *(short8*)dst = *(short8*)&v[0];
        *(short8*)(dst + 8) = *(short8*)&v[8];
    }
}

// -------- Phase B pass 1: flash attention over a j-stripe (barrier-free j-loop) --------
__global__ __launch_bounds__(256) void attn_kernel(
    const u64* __restrict__ msk,       // N x N/64 adjacency bits
    const short* __restrict__ h_bf,    // B,N,C
    const short* __restrict__ hT_bf,   // B,C,N
    const short* __restrict__ a_srcb,  // N,C
    const float* __restrict__ e2,      // B,N
    float* __restrict__ part_y,        // [S,B,N,C] or out [B,N,C] if mode
    float* __restrict__ part_m,        // [S,B,N]
    float* __restrict__ part_l,        // [S,B,N]
    int JS, int mode)
{
    __shared__ short lds_p[4][16 * 72];   // wave-private P tiles
    __shared__ float lds_e2[4][512];      // wave-private e2 stripe

    const int tid = threadIdx.x;
    const int wave = tid >> 6;
    const int lane = tid & 63;
    const int cl = lane & 15;
    const int rg = lane >> 4;
    const int b = wave;
    const int i0 = blockIdx.x * 16;
    const int jbeg = blockIdx.y * JS;
    const bool e2lds = (JS <= 512);

    if (e2lds) {
        for (int q = lane * 4; q < JS; q += 256)
            *(float4*)&lds_e2[wave][q] = *(const float4*)(e2 + (size_t)b * N + jbeg + q);
        // wave-private: no barrier needed (in-wave LDS ordering)
    }

    const short* hrow = h_bf + ((size_t)b * N + i0 + cl) * C;
    short8 af0 = *(const short8*)(hrow + rg * 8);
    short8 af1 = *(const short8*)(hrow + 32 + rg * 8);

    const u64* mrow_base[4];
#pragma unroll
    for (int r = 0; r < 4; r++)
        mrow_base[r] = msk + (size_t)(i0 + rg * 4 + r) * (N / 64);

    f32x4 yacc[4];
#pragma unroll
    for (int t = 0; t < 4; t++) { f32x4 z = {0.f, 0.f, 0.f, 0.f}; yacc[t] = z; }
    float mrow[4] = {-1e30f, -1e30f, -1e30f, -1e30f};
    float lrow[4] = {0.f, 0.f, 0.f, 0.f};

    for (int j0 = jbeg; j0 < jbeg + JS; j0 += 64) {
        const int jb = j0 >> 6;
        unsigned mlo[4], mhi[4];
#pragma unroll
        for (int r = 0; r < 4; r++) {
            u64 m = mrow_base[r][jb];
            mlo[r] = (unsigned)m;
            mhi[r] = (unsigned)(m >> 32);
        }

        // S = H_i @ a_src^T
        f32x4 sacc[4];
#pragma unroll
        for (int t = 0; t < 4; t++) {
            f32x4 z = {0.f, 0.f, 0.f, 0.f};
            const short* arow = a_srcb + (size_t)(j0 + t * 16 + cl) * C + rg * 8;
            short8 b0 = *(const short8*)(arow);
            short8 b1 = *(const short8*)(arow + 32);
            z = MFMA16(af0, b0, z);
            z = MFMA16(af1, b1, z);
            sacc[t] = z;
        }

        float e2v[4];
#pragma unroll
        for (int t = 0; t < 4; t++)
            e2v[t] = e2lds ? lds_e2[wave][j0 - jbeg + t * 16 + cl]
                           : e2[(size_t)b * N + j0 + t * 16 + cl];

        float p[4][4];
        float mcur[4] = {-1e30f, -1e30f, -1e30f, -1e30f};
#pragma unroll
        for (int t = 0; t < 4; t++) {
#pragma unroll
            for (int r = 0; r < 4; r++) {
                float sv = sacc[t][r] + e2v[t];
                sv = (sv >= 0.f) ? sv : 0.01f * sv;
                unsigned bits = (t < 2) ? mlo[r] : mhi[r];
                bool adj = (bits >> ((t & 1) * 16 + cl)) & 1u;
                sv = adj ? sv : -1e15f;
                p[t][r] = sv;
                mcur[r] = fmaxf(mcur[r], sv);
            }
        }

        float alpha[4];
#pragma unroll
        for (int r = 0; r < 4; r++) {
            float mx = mcur[r];
#pragma unroll
            for (int off = 8; off; off >>= 1) mx = fmaxf(mx, __shfl_xor(mx, off, 64));
            float mnew = fmaxf(mrow[r], mx);
            alpha[r] = __expf(mrow[r] - mnew);
            mrow[r] = mnew;
            float ps = 0.f;
#pragma unroll
            for (int t = 0; t < 4; t++) {
                float pv = __expf(p[t][r] - mnew);
                p[t][r] = pv;
                ps += pv;
            }
#pragma unroll
            for (int off = 8; off; off >>= 1) ps += __shfl_xor(ps, off, 64);
            lrow[r] = lrow[r] * alpha[r] + ps;
        }

#pragma unroll
        for (int t = 0; t < 4; t++)
#pragma unroll
            for (int r = 0; r < 4; r++) yacc[t][r] *= alpha[r];

        short* lp = lds_p[wave];
#pragma unroll
        for (int t = 0; t < 4; t++)
#pragma unroll
            for (int r = 0; r < 4; r++)
                lp[(rg * 4 + r) * 72 + t * 16 + cl] = f2bf(p[t][r]);
        short8 pa0 = *(const short8*)(lp + cl * 72 + rg * 8);
        short8 pa1 = *(const short8*)(lp + cl * 72 + 32 + rg * 8);

#pragma unroll
        for (int t = 0; t < 4; t++) {
            const short* hc = hT_bf + (size_t)b * C * N + (size_t)(t * 16 + cl) * N + j0 + rg * 8;
            short8 h0 = *(const short8*)(hc);
            short8 h1 = *(const short8*)(hc + 32);
            yacc[t] = MFMA16(pa0, h0, yacc[t]);
            yacc[t] = MFMA16(pa1, h1, yacc[t]);
        }
    }

    if (mode) {
#pragma unroll
        for (int t = 0; t < 4; t++)
#pragma unroll
            for (int r = 0; r < 4; r++)
                part_y[((size_t)b * N + i0 + rg * 4 + r) * C + t * 16 + cl] =
                    yacc[t][r] / lrow[r];
    } else {
        size_t sb = (size_t)(blockIdx.y * B + b) * N;
#pragma unroll
        for (int t = 0; t < 4; t++)
#pragma unroll
            for (int r = 0; r < 4; r++)
                part_y[(sb + i0 + rg * 4 + r) * C + t * 16 + cl] = yacc[t][r];
        if (cl == 0) {
#pragma unroll
            for (int r = 0; r < 4; r++) {
                part_m[sb + i0 + rg * 4 + r] = mrow[r];
                part_l[sb + i0 + rg * 4 + r] = lrow[r];
            }
        }
    }
}

// -------- Phase B pass 2: merge stripes --------
__global__ __launch_bounds__(256) void combine_kernel(
    const float* __restrict__ part_y, const float* __restrict__ part_m,
    const float* __restrict__ part_l, float* __restrict__ out, int S)
{
    int g = blockIdx.x * 256 + threadIdx.x;
    int c = g & 63;
    int row = (g >> 6) & (N - 1);
    int b = g >> 18;
    int bn = b * N + row;
    float m = -1e30f;
    for (int s = 0; s < S; s++) m = fmaxf(m, part_m[s * (B * N) + bn]);
    float l = 0.f, y = 0.f;
    for (int s = 0; s < S; s++) {
        float w = __expf(part_m[s * (B * N) + bn] - m);
        l += part_l[s * (B * N) + bn] * w;
        y += part_y[((size_t)s * B * N + bn) * C + c] * w;
    }
    out[g] = y / l;
}

extern "C" void kernel_launch(void* const* d_in, const int* in_sizes, int n_in,
                              void* d_out, int out_size, void* d_ws, size_t ws_size,
                              hipStream_t stream) {
    const float* x      = (const float*)d_in[0];
    const float* dist   = (const float*)d_in[1];
    const float* proj_w = (const float*)d_in[2];
    const float* proj_b = (const float*)d_in[3];
    const float* a_w    = (const float*)d_in[4];
    float* out = (float*)d_out;

    char* ws = (char*)d_ws;
    short* h_bf   = (short*)(ws);                              // 2 MB
    short* hT_bf  = (short*)(ws + (2u << 20));                 // 2 MB
    short* a_srcb = (short*)(ws + (4u << 20));                 // 512 KB
    float* e2     = (float*)(ws + (4u << 20) + (512u << 10));  // 64 KB
    u64*   msk    = (u64*)  (ws + (5u << 20));                 // 2 MB
    float* part_m = (float*)(ws + (7u << 20));                 // 512 KB (S=8)
    float* part_l = (float*)(ws + (7u << 20) + (512u << 10));  // 512 KB
    float* part_y = (float*)(ws + (8u << 20));                 // S * 4 MB

    proj_kernel<<<N, 256, 0, stream>>>(x, proj_w, proj_b, a_w, h_bf, a_srcb, e2);
    transpose_kernel<<<dim3(N / 64, B), 256, 0, stream>>>(h_bf, hT_bf);
    mask_kernel<<<N / 4, 256, 0, stream>>>(dist, msk);

    int S = 8;
    while (S > 1 && (8u << 20) + (size_t)S * B * N * C * 4 > ws_size) S >>= 1;
    bool direct = ((8u << 20) + (size_t)B * N * C * 4 > ws_size);

    if (direct) {
        attn_kernel<<<dim3(N / 16, 1), 256, 0, stream>>>(
            msk, h_bf, hT_bf, a_srcb, e2, out, part_m, part_l, N, 1);
    } else {
        attn_kernel<<<dim3(N / 16, S), 256, 0, stream>>>(
            msk, h_bf, hT_bf, a_srcb, e2, part_y, part_m, part_l, N / S, 0);
        combine_kernel<<<(B * N * C) / 256, 256, 0, stream>>>(part_y, part_m, part_l, out, S);
    }
}